// Round 9
// baseline (253.514 us; speedup 1.0000x reference)
//
#include <hip/hip_runtime.h>

#define NP 128

// NT streaming kernel, maximal per-lane width: 16 lanes per ray, 8 consecutive
// samples per lane (two 16B NT loads per stream -> 12 loads, 192 B in flight
// per lane). Halves wave count and per-byte instruction issue vs the float4
// version; scan is a 7-mult in-register serial prefix + 4-step shfl scan over
// 16 lanes. All loads/stores non-temporal (round-7 win: bypassing the L2/L3
// allocation path broke the 2.9 TB/s cache-path wall).
typedef float vfloat4 __attribute__((ext_vector_type(4)));

__device__ __forceinline__ vfloat4 ntload4(const float* p) {
    return __builtin_nontemporal_load((const vfloat4*)p);
}
__device__ __forceinline__ void ntstore4(float* p, vfloat4 v) {
    __builtin_nontemporal_store(v, (vfloat4*)p);
}

__global__ __launch_bounds__(256) void calc_ray_color_kernel(
    const float* __restrict__ rgb,      // [3, NR, NP]
    const float* __restrict__ density,  // [NR, NP]
    const float* __restrict__ dists,    // [NR, NP]
    const float* __restrict__ zvals,    // [NR, NP]
    float* __restrict__ out,            // rgb_res[3*NR] | bg[NR] | depth[NR] | weight[NR*NP]
    int NR)
{
    const int tid = threadIdx.x;
    const int sub = tid & 15;                       // lane within the 16-lane ray group
    const int ray = blockIdx.x * 16 + (tid >> 4);   // 16 rays per 256-thread block
    if (ray >= NR) return;

    const size_t base    = (size_t)ray * NP + 8 * sub;
    const size_t cstride = (size_t)NR * NP;

    const vfloat4 denA = ntload4(density + base);
    const vfloat4 denB = ntload4(density + base + 4);
    const vfloat4 dstA = ntload4(dists + base);
    const vfloat4 dstB = ntload4(dists + base + 4);
    const vfloat4 zA   = ntload4(zvals + base);
    const vfloat4 zB   = ntload4(zvals + base + 4);
    const vfloat4 c0A  = ntload4(rgb + base);
    const vfloat4 c0B  = ntload4(rgb + base + 4);
    const vfloat4 c1A  = ntload4(rgb + base + cstride);
    const vfloat4 c1B  = ntload4(rgb + base + cstride + 4);
    const vfloat4 c2A  = ntload4(rgb + base + 2 * cstride);
    const vfloat4 c2B  = ntload4(rgb + base + 2 * cstride + 4);

    // alpha / survival for the lane's 8 samples (fully unrolled, static idx)
    float a[8], x[8];
    #pragma unroll
    for (int i = 0; i < 4; ++i) {
        a[i]     = 1.0f - __expf(-denA[i] * dstA[i]);
        a[i + 4] = 1.0f - __expf(-denB[i] * dstB[i]);
    }
    #pragma unroll
    for (int i = 0; i < 8; ++i) x[i] = 1.0f - a[i] + 1e-10f;

    // in-register inclusive prefix products of the 8 local samples
    float pre[8];
    pre[0] = x[0];
    #pragma unroll
    for (int i = 1; i < 8; ++i) pre[i] = pre[i - 1] * x[i];

    // inclusive prefix product across the 16-lane group (4 dependent steps)
    float p = pre[7];
    #pragma unroll
    for (int off = 1; off < 16; off <<= 1) {
        const float v = __shfl_up(p, off, 16);
        if (sub >= off) p *= v;
    }
    float excl = __shfl_up(p, 1, 16);
    if (sub == 0) excl = 1.0f;

    // weights: w_k = a_k * excl * prod(local x_{<k})
    float w[8];
    w[0] = a[0] * excl;
    #pragma unroll
    for (int i = 1; i < 8; ++i) w[i] = a[i] * (excl * pre[i - 1]);

    {
        vfloat4 wA, wB;
        wA.x = w[0]; wA.y = w[1]; wA.z = w[2]; wA.w = w[3];
        wB.x = w[4]; wB.y = w[5]; wB.z = w[6]; wB.w = w[7];
        ntstore4(out + (size_t)5 * NR + base,     wA);
        ntstore4(out + (size_t)5 * NR + base + 4, wB);
    }

    float sdep = 0.f, sacc = 0.f, s0 = 0.f, s1 = 0.f, s2 = 0.f;
    #pragma unroll
    for (int i = 0; i < 4; ++i) {
        sdep += w[i] * zA[i]  + w[i + 4] * zB[i];
        sacc += w[i]          + w[i + 4];
        s0   += w[i] * c0A[i] + w[i + 4] * c0B[i];
        s1   += w[i] * c1A[i] + w[i + 4] * c1B[i];
        s2   += w[i] * c2A[i] + w[i + 4] * c2B[i];
    }

    // butterfly reduce within the 16-lane group (xor off<16 stays in-group)
    #pragma unroll
    for (int off = 8; off >= 1; off >>= 1) {
        s0   += __shfl_xor(s0, off);
        s1   += __shfl_xor(s1, off);
        s2   += __shfl_xor(s2, off);
        sdep += __shfl_xor(sdep, off);
        sacc += __shfl_xor(sacc, off);
    }

    if (sub == 0) {
        __builtin_nontemporal_store(s0,          out + ray);
        __builtin_nontemporal_store(s1,          out + (size_t)NR + ray);
        __builtin_nontemporal_store(s2,          out + 2 * (size_t)NR + ray);
        __builtin_nontemporal_store(1.0f - sacc, out + 3 * (size_t)NR + ray);
        __builtin_nontemporal_store(sdep,        out + 4 * (size_t)NR + ray);
    }
}

extern "C" void kernel_launch(void* const* d_in, const int* in_sizes, int n_in,
                              void* d_out, int out_size, void* d_ws, size_t ws_size,
                              hipStream_t stream) {
    // d_in[0] = fg_vps  (UNUSED by reference — do not read)
    const float* rgb     = (const float*)d_in[1];
    const float* density = (const float*)d_in[2];
    const float* dists   = (const float*)d_in[3];
    const float* zvals   = (const float*)d_in[4];
    float* out = (float*)d_out;

    const int NR = in_sizes[2] / NP;   // density is [1,1,NR,NP]
    const int rays_per_block = 16;     // 256 threads = 16 ray-groups of 16 lanes
    const int grid = (NR + rays_per_block - 1) / rays_per_block;

    calc_ray_color_kernel<<<grid, 256, 0, stream>>>(rgb, density, dists, zvals, out, NR);
}